// Round 1
// baseline (50.397 us; speedup 1.0000x reference)
//
#include <hip/hip_runtime.h>

// Problem constants (match reference): B=128, T=512, DZ=512
#define BB 128
#define TT 512
#define DZ 512
#define NCHUNK 4                 // column chunks per batch row
#define DCHUNK (DZ / NCHUNK)     // 128 floats per chunk
// out[b,t,d] = init[b,d] + f[d] * prefixsum_{s<=t}(x[b,s])

__global__ __launch_bounds__(512) void lts_kernel(
    const float* __restrict__ t_in,   // (B, T)   [last dim of size 1 squeezed]
    const float* __restrict__ init,   // (B, DZ)
    const float* __restrict__ f,      // (DZ)
    float* __restrict__ out)          // (B, T, DZ)
{
    __shared__ float s[TT];

    const int tid = threadIdx.x;          // 0..511
    const int b   = blockIdx.x / NCHUNK;  // batch row
    const int c   = blockIdx.x % NCHUNK;  // column chunk

    // ---- Phase 1: inclusive prefix sum of x[b, :] into LDS ----
    s[tid] = t_in[b * TT + tid];
    __syncthreads();
#pragma unroll
    for (int off = 1; off < TT; off <<= 1) {
        float v = (tid >= off) ? s[tid - off] : 0.0f;
        __syncthreads();
        s[tid] += v;
        __syncthreads();
    }

    // ---- Phase 2: stream the (T x DCHUNK) output slice ----
    // Each thread owns one fixed float4 column: j = tid & 31 (32 float4 = 128 floats)
    const int j = tid & 31;               // float4 column within chunk
    const int d = c * DCHUNK + j * 4;     // starting scalar column

    const float4 f4 = *reinterpret_cast<const float4*>(&f[d]);
    const float4 i4 = *reinterpret_cast<const float4*>(&init[b * DZ + d]);

    const int trow_base = tid >> 5;       // 0..15
    float* out_b = out + (size_t)b * TT * DZ + d;

#pragma unroll 4
    for (int iter = 0; iter < 32; ++iter) {
        const int t = iter * 16 + trow_base;   // 0..511, covers all t
        const float st = s[t];                 // wave-broadcast read
        float4 o;
        o.x = i4.x + f4.x * st;
        o.y = i4.y + f4.y * st;
        o.z = i4.z + f4.z * st;
        o.w = i4.w + f4.w * st;
        *reinterpret_cast<float4*>(&out_b[(size_t)t * DZ]) = o;
    }
}

extern "C" void kernel_launch(void* const* d_in, const int* in_sizes, int n_in,
                              void* d_out, int out_size, void* d_ws, size_t ws_size,
                              hipStream_t stream) {
    const float* t_in = (const float*)d_in[0];  // (B,T,1) -> (B,T)
    const float* init = (const float*)d_in[1];  // (B,DZ)
    const float* f    = (const float*)d_in[2];  // (1,DZ) -> (DZ)
    float* out        = (float*)d_out;          // (B,T,DZ)

    lts_kernel<<<dim3(BB * NCHUNK), dim3(512), 0, stream>>>(t_in, init, f, out);
}

// Round 2
// 26.309 us; speedup vs baseline: 1.9156x; 1.9156x over previous
//
#include <hip/hip_runtime.h>

// Problem constants (match reference): B=128, T=512, DZ=512
#define BB 128
#define TT 512
#define DZ 512
#define ROWS_PER_BLOCK 32
#define NBLOCKS ((BB * TT) / ROWS_PER_BLOCK)   // 2048 blocks, 8 per CU
// out[b,t,d] = init[b,d] + f[d] * prefixsum_{s<=t}(x[b,s])

__global__ __launch_bounds__(256, 8) void lts_kernel(
    const float* __restrict__ t_in,   // (B, T)
    const float* __restrict__ init,   // (B, DZ)
    const float* __restrict__ f,      // (DZ)
    float* __restrict__ out)          // (B, T, DZ)
{
    __shared__ float s[TT];

    const int tid = threadIdx.x;                 // 0..255
    const int g0  = blockIdx.x * ROWS_PER_BLOCK; // global row base (b*T + t0)
    const int b   = g0 >> 9;                     // batch (T = 512)
    const int t0  = g0 & (TT - 1);               // local time base

    // ---- Prologue: wave 0 computes the full inclusive scan of t_in[b, :] ----
    // 8 elements/lane serial scan + 6-step shfl_up wave scan. No barriers here.
    if (tid < 64) {
        const float* xb = t_in + b * TT + tid * 8;
        const float4 a = *reinterpret_cast<const float4*>(xb);
        const float4 c = *reinterpret_cast<const float4*>(xb + 4);
        const float v0 = a.x;
        const float v1 = v0 + a.y;
        const float v2 = v1 + a.z;
        const float v3 = v2 + a.w;
        const float v4 = v3 + c.x;
        const float v5 = v4 + c.y;
        const float v6 = v5 + c.z;
        const float v7 = v6 + c.w;
        float run = v7;
#pragma unroll
        for (int off = 1; off < 64; off <<= 1) {
            const float y = __shfl_up(run, off, 64);
            if (tid >= off) run += y;
        }
        const float excl = run - v7;             // exclusive prefix of lane totals
        float4 o0, o1;
        o0.x = v0 + excl; o0.y = v1 + excl; o0.z = v2 + excl; o0.w = v3 + excl;
        o1.x = v4 + excl; o1.y = v5 + excl; o1.z = v6 + excl; o1.w = v7 + excl;
        *reinterpret_cast<float4*>(&s[tid * 8])     = o0;
        *reinterpret_cast<float4*>(&s[tid * 8 + 4]) = o1;
    }

    // ---- Per-thread fixed column quad over the full 512-float row ----
    const int q = tid & 127;    // float4 column index, 0..127 (covers full row)
    const int h = tid >> 7;     // 0..1 : row parity handled by this half-block
    const int d = q * 4;

    const float4 f4 = *reinterpret_cast<const float4*>(&f[d]);
    const float4 i4 = *reinterpret_cast<const float4*>(&init[b * DZ + d]);

    __syncthreads();

    // ---- Stream 32 contiguous rows; each wave store = 1 KB contiguous ----
    float* outp = out + ((size_t)(g0 + h) * DZ + d);
#pragma unroll
    for (int iter = 0; iter < ROWS_PER_BLOCK / 2; ++iter) {
        const float st = s[t0 + iter * 2 + h];   // wave-uniform LDS broadcast
        float4 o;
        o.x = i4.x + f4.x * st;
        o.y = i4.y + f4.y * st;
        o.z = i4.z + f4.z * st;
        o.w = i4.w + f4.w * st;
        *reinterpret_cast<float4*>(outp) = o;
        outp += 2 * DZ;
    }
}

extern "C" void kernel_launch(void* const* d_in, const int* in_sizes, int n_in,
                              void* d_out, int out_size, void* d_ws, size_t ws_size,
                              hipStream_t stream) {
    const float* t_in = (const float*)d_in[0];  // (B,T,1) -> (B,T)
    const float* init = (const float*)d_in[1];  // (B,DZ)
    const float* f    = (const float*)d_in[2];  // (1,DZ) -> (DZ)
    float* out        = (float*)d_out;          // (B,T,DZ)

    lts_kernel<<<dim3(NBLOCKS), dim3(256), 0, stream>>>(t_in, init, f, out);
}